// Round 1
// baseline (3695.185 us; speedup 1.0000x reference)
//
#include <hip/hip_runtime.h>
#include <math.h>

#define TOK 8192   // B*S tokens
#define DIM 256    // hidden
#define NE  32     // experts
#define NK  4      // top-k
#define NF  1024   // ffn dim

// ---------------- Router ----------------
// 256 blocks x 256 threads; each block handles 32 tokens.
__global__ __launch_bounds__(256) void router_kernel(
    const float* __restrict__ x, const float* __restrict__ rw,
    int* __restrict__ counts, float* __restrict__ psum,
    int* __restrict__ etok, float* __restrict__ ewt)
{
  __shared__ float xs[32][DIM + 4];
  __shared__ float ws[NE][DIM + 4];
  __shared__ float lg[32][NE];
  __shared__ int hist[NE];
  __shared__ int base[NE];

  const int tid = threadIdx.x;
  const int t0 = blockIdx.x * 32;

  {
    const float4* xg = (const float4*)(x + (size_t)t0 * DIM);
    for (int i = tid; i < 32 * (DIM/4); i += 256) {
      int t = i / (DIM/4), c = i % (DIM/4);
      *(float4*)&xs[t][c*4] = xg[t*(DIM/4)+c];
    }
    const float4* wgp = (const float4*)rw;
    for (int i = tid; i < NE * (DIM/4); i += 256) {
      int e = i / (DIM/4), c = i % (DIM/4);
      *(float4*)&ws[e][c*4] = wgp[e*(DIM/4)+c];
    }
  }
  if (tid < NE) hist[tid] = 0;
  __syncthreads();

  // logits: 32 tokens x 32 experts = 1024 dots, 4 per thread
  for (int i = 0; i < 4; i++) {
    int idx = i*256 + tid;
    int t = idx >> 5, e = idx & 31;
    float acc = 0.f;
    for (int c = 0; c < DIM/4; c++) {
      float4 a = *(const float4*)&xs[t][c*4];
      float4 b = *(const float4*)&ws[e][c*4];
      acc += a.x*b.x + a.y*b.y + a.z*b.z + a.w*b.w;
    }
    lg[t][e] = acc;
  }
  __syncthreads();

  int ids[NK]; int slots[NK]; float wts[NK];
  if (tid < 32) {
    const int t = tid;
    float l[NE];
    #pragma unroll
    for (int e = 0; e < NE; e++) l[e] = lg[t][e];
    unsigned mask = 0;
    float vals[NK];
    #pragma unroll
    for (int k = 0; k < NK; k++) {
      float best = -INFINITY; int bi = 0;
      for (int e = 0; e < NE; e++)
        if (!((mask >> e) & 1u) && l[e] > best) { best = l[e]; bi = e; }
      mask |= 1u << bi; vals[k] = best; ids[k] = bi;
    }
    float s4 = 0.f;
    #pragma unroll
    for (int k = 0; k < NK; k++) { wts[k] = __expf(vals[k] - vals[0]); s4 += wts[k]; }
    #pragma unroll
    for (int k = 0; k < NK; k++) wts[k] /= s4;
    // full softmax (vals[0] is the global max)
    float s = 0.f;
    for (int e = 0; e < NE; e++) { l[e] = __expf(l[e] - vals[0]); s += l[e]; }
    float inv = 1.f / s;
    for (int e = 0; e < NE; e++) lg[t][e] = l[e] * inv;  // overwrite own row with probs
    #pragma unroll
    for (int k = 0; k < NK; k++) slots[k] = atomicAdd(&hist[ids[k]], 1);
  }
  __syncthreads();
  if (tid < NE) {
    float s = 0.f;
    for (int t = 0; t < 32; t++) s += lg[t][tid];
    atomicAdd(&psum[tid], s);
    int h = hist[tid];
    base[tid] = h ? atomicAdd(&counts[tid], h) : 0;
  }
  __syncthreads();
  if (tid < 32) {
    #pragma unroll
    for (int k = 0; k < NK; k++) {
      int p = base[ids[k]] + slots[k];
      etok[(size_t)ids[k]*TOK + p] = t0 + tid;
      ewt [(size_t)ids[k]*TOK + p] = wts[k];
    }
  }
}

// ---------------- Aux loss ----------------
__global__ void aux_kernel(const int* __restrict__ counts,
                           const float* __restrict__ psum,
                           float* __restrict__ aux_out)
{
  int tid = threadIdx.x; // 64 threads
  float v = 0.f;
  if (tid < NE) v = (counts[tid] / (float)TOK) * (psum[tid] / (float)TOK);
  #pragma unroll
  for (int off = 32; off; off >>= 1) v += __shfl_down(v, off);
  if (tid == 0) aux_out[0] = (float)NE * v;
}

// ---------------- Expert FFN (gathered, sparse) ----------------
// grid (256 tiles, 32 experts); block 256 threads handles 32 tokens of one expert.
__global__ __launch_bounds__(256) void expert_kernel(
    const float* __restrict__ x,
    const float* __restrict__ wg_, const float* __restrict__ wu_,
    const float* __restrict__ wd_,
    const int* __restrict__ counts,
    const int* __restrict__ etok, const float* __restrict__ ewt,
    float* __restrict__ out)
{
  const int e = blockIdx.y;
  const int cnt = counts[e];
  const int t0 = blockIdx.x * 32;
  if (t0 >= cnt) return;

  __shared__ float xs[32][DIM];   // 32 KB
  __shared__ float hs[32][64];    // 8 KB  (total 40 KB -> 4 blocks/CU)

  const int tid = threadIdx.x;
  const int* el = etok + (size_t)e * TOK;

  // gather x tile (zero-pad past cnt)
  for (int i = tid; i < 32 * (DIM/4); i += 256) {
    int t = i >> 6, c = i & 63;
    int gt = t0 + t;
    float4 v = make_float4(0.f, 0.f, 0.f, 0.f);
    if (gt < cnt) {
      int tok = el[gt];
      v = ((const float4*)(x + (size_t)tok * DIM))[c];
    }
    *(float4*)&xs[t][c*4] = v;
  }

  float acc0[16], acc1[16];
  #pragma unroll
  for (int j = 0; j < 16; j++) { acc0[j] = 0.f; acc1[j] = 0.f; }

  const int fi = tid & 63;          // f within chunk (h-phase)
  const int tg = tid >> 6;          // 4 token-groups of 8 (h-phase)
  const int dh = (tid & 127) * 2;   // down-phase: this thread's d, d+1
  const int th = (tid >> 7) * 16;   // down-phase: token half (0 or 16)

  __syncthreads();

  for (int f0 = 0; f0 < NF; f0 += 64) {
    // --- gate/up dots: thread owns f = f0+fi for 8 tokens ---
    const float4* wg4 = (const float4*)(wg_ + ((size_t)e*NF + f0 + fi) * DIM);
    const float4* wu4 = (const float4*)(wu_ + ((size_t)e*NF + f0 + fi) * DIM);
    float g[8], u[8];
    #pragma unroll
    for (int j = 0; j < 8; j++) { g[j] = 0.f; u[j] = 0.f; }
    for (int c = 0; c < DIM/4; c++) {
      float4 a = wg4[c], b = wu4[c];
      #pragma unroll
      for (int j = 0; j < 8; j++) {
        float4 xv = *(const float4*)&xs[tg*8 + j][c*4];  // wave-broadcast
        g[j] += xv.x*a.x + xv.y*a.y + xv.z*a.z + xv.w*a.w;
        u[j] += xv.x*b.x + xv.y*b.y + xv.z*b.z + xv.w*b.w;
      }
    }
    __syncthreads();   // previous chunk's hs fully consumed
    #pragma unroll
    for (int j = 0; j < 8; j++) {
      float gv = g[j];
      float sg = gv / (1.f + __expf(-gv));   // silu
      hs[tg*8 + j][fi] = sg * u[j];
    }
    __syncthreads();
    // --- down accumulate: thread owns (d, d+1) x 16 tokens ---
    const float* wd0 = wd_ + ((size_t)e*DIM + dh) * NF + f0;
    const float* wd1 = wd0 + NF;
    #pragma unroll
    for (int fj = 0; fj < 16; fj++) {
      float4 w0 = *(const float4*)&wd0[fj*4];
      float4 w1 = *(const float4*)&wd1[fj*4];
      #pragma unroll
      for (int j = 0; j < 16; j++) {
        float4 hv = *(const float4*)&hs[th + j][fj*4];   // wave-broadcast
        acc0[j] += hv.x*w0.x + hv.y*w0.y + hv.z*w0.z + hv.w*w0.w;
        acc1[j] += hv.x*w1.x + hv.y*w1.y + hv.z*w1.z + hv.w*w1.w;
      }
    }
  }

  // epilogue: weighted atomic scatter (each out element hit exactly K times)
  #pragma unroll
  for (int j = 0; j < 16; j++) {
    int gt = t0 + th + j;
    if (gt < cnt) {
      int tok = el[gt];
      float w = ewt[(size_t)e*TOK + gt];
      atomicAdd(&out[(size_t)tok*DIM + dh],     w * acc0[j]);
      atomicAdd(&out[(size_t)tok*DIM + dh + 1], w * acc1[j]);
    }
  }
}

extern "C" void kernel_launch(void* const* d_in, const int* in_sizes, int n_in,
                              void* d_out, int out_size, void* d_ws, size_t ws_size,
                              hipStream_t stream)
{
  const float* x  = (const float*)d_in[0];
  const float* rw = (const float*)d_in[1];
  const float* wg = (const float*)d_in[2];
  const float* wu = (const float*)d_in[3];
  const float* wd = (const float*)d_in[4];
  float* out = (float*)d_out;

  // workspace layout (~2.1 MB): counts[32] | psum[32] | etok[E*T] | ewt[E*T]
  int*   counts = (int*)d_ws;
  float* psum   = (float*)((char*)d_ws + 128);
  int*   etok   = (int*)((char*)d_ws + 256);
  float* ewt    = (float*)((char*)d_ws + 256 + (size_t)NE*TOK*4);

  hipMemsetAsync(d_ws, 0, 256, stream);                         // counts + psum
  hipMemsetAsync(d_out, 0, (size_t)out_size * 4, stream);       // out accumulators + aux

  router_kernel<<<TOK/32, 256, 0, stream>>>(x, rw, counts, psum, etok, ewt);
  aux_kernel<<<1, 64, 0, stream>>>(counts, psum, out + (size_t)TOK*DIM);
  expert_kernel<<<dim3(TOK/32, NE), 256, 0, stream>>>(x, wg, wu, wd, counts, etok, ewt, out);
}

// Round 2
// 879.312 us; speedup vs baseline: 4.2024x; 4.2024x over previous
//
#include <hip/hip_runtime.h>
#include <math.h>

#define TOK 8192   // B*S tokens
#define DIM 256    // hidden
#define NE  32     // experts
#define NK  4      // top-k
#define NF  1024   // ffn dim

typedef __bf16 bf16x8 __attribute__((ext_vector_type(8)));
typedef float  f32x4  __attribute__((ext_vector_type(4)));

__device__ __forceinline__ unsigned short f2b(float f) {
  unsigned u = __builtin_bit_cast(unsigned, f);
  unsigned r = (u + 0x7FFFu + ((u >> 16) & 1u)) >> 16;   // RNE
  return (unsigned short)r;
}

// ---------------- fp32 -> bf16 weight conversion ----------------
__global__ __launch_bounds__(256) void cvt_kernel(const float* __restrict__ src,
                                                  unsigned short* __restrict__ dst, int n4)
{
  int i = blockIdx.x * 256 + threadIdx.x;
  int stride = gridDim.x * 256;
  for (; i < n4; i += stride) {
    float4 v = ((const float4*)src)[i];
    ushort4 b;
    b.x = f2b(v.x); b.y = f2b(v.y); b.z = f2b(v.z); b.w = f2b(v.w);
    ((ushort4*)dst)[i] = b;
  }
}

// ---------------- Router (fp32, exact top-k match) ----------------
__global__ __launch_bounds__(256) void router_kernel(
    const float* __restrict__ x, const float* __restrict__ rw,
    int* __restrict__ counts, float* __restrict__ psum,
    int* __restrict__ etok, float* __restrict__ ewt)
{
  __shared__ float xs[32][DIM + 4];
  __shared__ float ws[NE][DIM + 4];
  __shared__ float lg[32][NE];
  __shared__ int hist[NE];
  __shared__ int base[NE];

  const int tid = threadIdx.x;
  const int t0 = blockIdx.x * 32;

  {
    const float4* xg = (const float4*)(x + (size_t)t0 * DIM);
    for (int i = tid; i < 32 * (DIM/4); i += 256) {
      int t = i / (DIM/4), c = i % (DIM/4);
      *(float4*)&xs[t][c*4] = xg[t*(DIM/4)+c];
    }
    const float4* wgp = (const float4*)rw;
    for (int i = tid; i < NE * (DIM/4); i += 256) {
      int e = i / (DIM/4), c = i % (DIM/4);
      *(float4*)&ws[e][c*4] = wgp[e*(DIM/4)+c];
    }
  }
  if (tid < NE) hist[tid] = 0;
  __syncthreads();

  for (int i = 0; i < 4; i++) {
    int idx = i*256 + tid;
    int t = idx >> 5, e = idx & 31;
    float acc = 0.f;
    for (int c = 0; c < DIM/4; c++) {
      float4 a = *(const float4*)&xs[t][c*4];
      float4 b = *(const float4*)&ws[e][c*4];
      acc += a.x*b.x + a.y*b.y + a.z*b.z + a.w*b.w;
    }
    lg[t][e] = acc;
  }
  __syncthreads();

  int ids[NK]; int slots[NK]; float wts[NK];
  if (tid < 32) {
    const int t = tid;
    float l[NE];
    #pragma unroll
    for (int e = 0; e < NE; e++) l[e] = lg[t][e];
    unsigned mask = 0;
    float vals[NK];
    #pragma unroll
    for (int k = 0; k < NK; k++) {
      float best = -INFINITY; int bi = 0;
      for (int e = 0; e < NE; e++)
        if (!((mask >> e) & 1u) && l[e] > best) { best = l[e]; bi = e; }
      mask |= 1u << bi; vals[k] = best; ids[k] = bi;
    }
    float s4 = 0.f;
    #pragma unroll
    for (int k = 0; k < NK; k++) { wts[k] = __expf(vals[k] - vals[0]); s4 += wts[k]; }
    #pragma unroll
    for (int k = 0; k < NK; k++) wts[k] /= s4;
    float s = 0.f;
    for (int e = 0; e < NE; e++) { l[e] = __expf(l[e] - vals[0]); s += l[e]; }
    float inv = 1.f / s;
    for (int e = 0; e < NE; e++) lg[t][e] = l[e] * inv;
    #pragma unroll
    for (int k = 0; k < NK; k++) slots[k] = atomicAdd(&hist[ids[k]], 1);
  }
  __syncthreads();
  if (tid < NE) {
    float s = 0.f;
    for (int t = 0; t < 32; t++) s += lg[t][tid];
    atomicAdd(&psum[tid], s);
    int h = hist[tid];
    base[tid] = h ? atomicAdd(&counts[tid], h) : 0;
  }
  __syncthreads();
  if (tid < 32) {
    #pragma unroll
    for (int k = 0; k < NK; k++) {
      int p = base[ids[k]] + slots[k];
      etok[(size_t)ids[k]*TOK + p] = t0 + tid;
      ewt [(size_t)ids[k]*TOK + p] = wts[k];
    }
  }
}

// ---------------- Aux loss ----------------
__global__ void aux_kernel(const int* __restrict__ counts,
                           const float* __restrict__ psum,
                           float* __restrict__ aux_out)
{
  int tid = threadIdx.x;
  float v = 0.f;
  if (tid < NE) v = (counts[tid] / (float)TOK) * (psum[tid] / (float)TOK);
  #pragma unroll
  for (int off = 32; off; off >>= 1) v += __shfl_down(v, off);
  if (tid == 0) aux_out[0] = (float)NE * v;
}

// ---------------- Expert FFN: bf16 MFMA ----------------
// grid (TOK/32, NE); 256 thr = 4 waves; 32-token tile of one expert.
// Wave w: row-tile rt=w&1 (tokens rt*16..+16), col-group cg=w>>1.
__global__ __launch_bounds__(256) void expert_mfma_kernel(
    const float* __restrict__ x,
    const unsigned short* __restrict__ wgb,
    const unsigned short* __restrict__ wub,
    const unsigned short* __restrict__ wdb,
    const int* __restrict__ counts,
    const int* __restrict__ etok, const float* __restrict__ ewt,
    float* __restrict__ out)
{
  const int e = blockIdx.y;
  const int cnt = counts[e];
  const int t0 = blockIdx.x * 32;
  if (t0 >= cnt) return;

  __shared__ unsigned short xs[32][DIM + 8];  // bf16 X tile, padded
  __shared__ unsigned short hs[32][64 + 8];   // bf16 H chunk, padded
  __shared__ int   lel[32];
  __shared__ float lwt[32];

  const int tid  = threadIdx.x;
  const int lane = tid & 63;
  const int wv   = tid >> 6;
  const int rt   = wv & 1;     // token row-tile
  const int cg   = wv >> 1;    // column group
  const int q    = lane >> 4;  // quad 0..3
  const int ln   = lane & 15;

  const int* el = etok + (size_t)e * TOK;

  if (tid < 32) {
    int gt = t0 + tid;
    lel[tid] = (gt < cnt) ? el[gt] : -1;
    lwt[tid] = (gt < cnt) ? ewt[(size_t)e*TOK + gt] : 0.f;
  }
  __syncthreads();

  // gather X rows, convert fp32->bf16 into LDS (8 threads per row)
  {
    int row = tid >> 3, seg = tid & 7;
    int tok = lel[row];
    const float4* xg = (const float4*)(x + (size_t)(tok < 0 ? 0 : tok) * DIM);
    #pragma unroll
    for (int s = 0; s < 8; s++) {
      int c4 = seg * 8 + s;                      // float4 index 0..63
      float4 v = (tok >= 0) ? xg[c4] : make_float4(0.f,0.f,0.f,0.f);
      ushort4 b;
      b.x = f2b(v.x); b.y = f2b(v.y); b.z = f2b(v.z); b.w = f2b(v.w);
      *(ushort4*)&xs[row][c4*4] = b;
    }
  }
  __syncthreads();

  // preload X A-fragments for this wave's row-tile (reused all 16 chunks)
  bf16x8 xf[8];
  #pragma unroll
  for (int i = 0; i < 8; i++)
    xf[i] = *(const bf16x8*)&xs[rt*16 + ln][i*32 + q*8];

  f32x4 oacc[8];
  #pragma unroll
  for (int c = 0; c < 8; c++) oacc[c] = (f32x4){0.f,0.f,0.f,0.f};

  for (int f0 = 0; f0 < NF; f0 += 64) {
    // ---- gate/up: this wave covers f columns [f0+cg*32, f0+cg*32+32) ----
    f32x4 gacc[2], uacc[2];
    #pragma unroll
    for (int ct = 0; ct < 2; ct++) { gacc[ct] = (f32x4){0,0,0,0}; uacc[ct] = (f32x4){0,0,0,0}; }
    #pragma unroll
    for (int ct = 0; ct < 2; ct++) {
      const unsigned short* wgr = wgb + ((size_t)e*NF + f0 + cg*32 + ct*16 + ln) * DIM + q*8;
      const unsigned short* wur = wub + ((size_t)e*NF + f0 + cg*32 + ct*16 + ln) * DIM + q*8;
      #pragma unroll
      for (int i = 0; i < 8; i++) {
        bf16x8 bg = *(const bf16x8*)(wgr + i*32);
        bf16x8 bu = *(const bf16x8*)(wur + i*32);
        gacc[ct] = __builtin_amdgcn_mfma_f32_16x16x32_bf16(xf[i], bg, gacc[ct], 0, 0, 0);
        uacc[ct] = __builtin_amdgcn_mfma_f32_16x16x32_bf16(xf[i], bu, uacc[ct], 0, 0, 0);
      }
    }
    __syncthreads();   // previous chunk's hs fully consumed
    #pragma unroll
    for (int ct = 0; ct < 2; ct++) {
      #pragma unroll
      for (int r = 0; r < 4; r++) {
        float g = gacc[ct][r], u = uacc[ct][r];
        float h = (g / (1.f + __expf(-g))) * u;   // silu(g)*u
        hs[rt*16 + q*4 + r][cg*32 + ct*16 + ln] = f2b(h);
      }
    }
    __syncthreads();
    // ---- down: this wave covers d columns [cg*128, cg*128+128) ----
    #pragma unroll
    for (int kk = 0; kk < 2; kk++) {
      bf16x8 af = *(const bf16x8*)&hs[rt*16 + ln][kk*32 + q*8];
      #pragma unroll
      for (int ct = 0; ct < 8; ct++) {
        const unsigned short* wdr =
            wdb + ((size_t)e*DIM + cg*128 + ct*16 + ln) * NF + f0 + kk*32 + q*8;
        bf16x8 bf = *(const bf16x8*)wdr;
        oacc[ct] = __builtin_amdgcn_mfma_f32_16x16x32_bf16(af, bf, oacc[ct], 0, 0, 0);
      }
    }
  }

  // epilogue: weighted atomic scatter
  #pragma unroll
  for (int ct = 0; ct < 8; ct++) {
    int d = cg*128 + ct*16 + ln;
    #pragma unroll
    for (int r = 0; r < 4; r++) {
      int tl = rt*16 + q*4 + r;
      int tok = lel[tl];
      if (tok >= 0)
        atomicAdd(&out[(size_t)tok*DIM + d], lwt[tl] * oacc[ct][r]);
    }
  }
}

// ---------------- fp32 fallback expert kernel (if ws too small for bf16 weights) ----------------
__global__ __launch_bounds__(256) void expert_kernel_f32(
    const float* __restrict__ x,
    const float* __restrict__ wg_, const float* __restrict__ wu_,
    const float* __restrict__ wd_,
    const int* __restrict__ counts,
    const int* __restrict__ etok, const float* __restrict__ ewt,
    float* __restrict__ out)
{
  const int e = blockIdx.y;
  const int cnt = counts[e];
  const int t0 = blockIdx.x * 32;
  if (t0 >= cnt) return;

  __shared__ float xs[32][DIM];
  __shared__ float hs[32][64];

  const int tid = threadIdx.x;
  const int* el = etok + (size_t)e * TOK;

  for (int i = tid; i < 32 * (DIM/4); i += 256) {
    int t = i >> 6, c = i & 63;
    int gt = t0 + t;
    float4 v = make_float4(0.f, 0.f, 0.f, 0.f);
    if (gt < cnt) {
      int tok = el[gt];
      v = ((const float4*)(x + (size_t)tok * DIM))[c];
    }
    *(float4*)&xs[t][c*4] = v;
  }

  float acc0[16], acc1[16];
  #pragma unroll
  for (int j = 0; j < 16; j++) { acc0[j] = 0.f; acc1[j] = 0.f; }

  const int fi = tid & 63;
  const int tg = tid >> 6;
  const int dh = (tid & 127) * 2;
  const int th = (tid >> 7) * 16;

  __syncthreads();

  for (int f0 = 0; f0 < NF; f0 += 64) {
    const float4* wg4 = (const float4*)(wg_ + ((size_t)e*NF + f0 + fi) * DIM);
    const float4* wu4 = (const float4*)(wu_ + ((size_t)e*NF + f0 + fi) * DIM);
    float g[8], u[8];
    #pragma unroll
    for (int j = 0; j < 8; j++) { g[j] = 0.f; u[j] = 0.f; }
    for (int c = 0; c < DIM/4; c++) {
      float4 a = wg4[c], b = wu4[c];
      #pragma unroll
      for (int j = 0; j < 8; j++) {
        float4 xv = *(const float4*)&xs[tg*8 + j][c*4];
        g[j] += xv.x*a.x + xv.y*a.y + xv.z*a.z + xv.w*a.w;
        u[j] += xv.x*b.x + xv.y*b.y + xv.z*b.z + xv.w*b.w;
      }
    }
    __syncthreads();
    #pragma unroll
    for (int j = 0; j < 8; j++) {
      float gv = g[j];
      hs[tg*8 + j][fi] = (gv / (1.f + __expf(-gv))) * u[j];
    }
    __syncthreads();
    const float* wd0 = wd_ + ((size_t)e*DIM + dh) * NF + f0;
    const float* wd1 = wd0 + NF;
    #pragma unroll
    for (int fj = 0; fj < 16; fj++) {
      float4 w0 = *(const float4*)&wd0[fj*4];
      float4 w1 = *(const float4*)&wd1[fj*4];
      #pragma unroll
      for (int j = 0; j < 16; j++) {
        float4 hv = *(const float4*)&hs[th + j][fj*4];
        acc0[j] += hv.x*w0.x + hv.y*w0.y + hv.z*w0.z + hv.w*w0.w;
        acc1[j] += hv.x*w1.x + hv.y*w1.y + hv.z*w1.z + hv.w*w1.w;
      }
    }
  }

  #pragma unroll
  for (int j = 0; j < 16; j++) {
    int gt = t0 + th + j;
    if (gt < cnt) {
      int tok = el[gt];
      float w = ewt[(size_t)e*TOK + gt];
      atomicAdd(&out[(size_t)tok*DIM + dh],     w * acc0[j]);
      atomicAdd(&out[(size_t)tok*DIM + dh + 1], w * acc1[j]);
    }
  }
}

extern "C" void kernel_launch(void* const* d_in, const int* in_sizes, int n_in,
                              void* d_out, int out_size, void* d_ws, size_t ws_size,
                              hipStream_t stream)
{
  const float* x  = (const float*)d_in[0];
  const float* rw = (const float*)d_in[1];
  const float* wg = (const float*)d_in[2];
  const float* wu = (const float*)d_in[3];
  const float* wd = (const float*)d_in[4];
  float* out = (float*)d_out;

  const size_t W = (size_t)NE * NF * DIM;   // elems per weight tensor
  // ws layout: counts[32] | psum[32] | etok | ewt | wg_b | wu_b | wd_b
  int*   counts = (int*)d_ws;
  float* psum   = (float*)((char*)d_ws + 128);
  int*   etok   = (int*)((char*)d_ws + 256);
  float* ewt    = (float*)((char*)d_ws + 256 + (size_t)NE*TOK*4);
  unsigned short* wgb = (unsigned short*)((char*)d_ws + 256 + (size_t)NE*TOK*8);
  unsigned short* wub = wgb + W;
  unsigned short* wdb = wub + W;
  const size_t need = 256 + (size_t)NE*TOK*8 + 3*W*2;

  hipMemsetAsync(d_ws, 0, 256, stream);
  hipMemsetAsync(d_out, 0, (size_t)out_size * 4, stream);

  router_kernel<<<TOK/32, 256, 0, stream>>>(x, rw, counts, psum, etok, ewt);
  aux_kernel<<<1, 64, 0, stream>>>(counts, psum, out + (size_t)TOK*DIM);

  if (ws_size >= need) {
    const int n4 = (int)(W / 4);
    cvt_kernel<<<2048, 256, 0, stream>>>(wg, wgb, n4);
    cvt_kernel<<<2048, 256, 0, stream>>>(wu, wub, n4);
    cvt_kernel<<<2048, 256, 0, stream>>>(wd, wdb, n4);
    expert_mfma_kernel<<<dim3(TOK/32, NE), 256, 0, stream>>>(
        x, wgb, wub, wdb, counts, etok, ewt, out);
  } else {
    expert_kernel_f32<<<dim3(TOK/32, NE), 256, 0, stream>>>(
        x, wg, wu, wd, counts, etok, ewt, out);
  }
}

// Round 3
// 544.359 us; speedup vs baseline: 6.7881x; 1.6153x over previous
//
#include <hip/hip_runtime.h>
#include <math.h>

#define TOK 8192   // B*S tokens
#define DIM 256    // hidden
#define NE  32     // experts
#define NK  4      // top-k
#define NF  1024   // ffn dim

typedef __bf16 bf16x8 __attribute__((ext_vector_type(8)));
typedef float  f32x4  __attribute__((ext_vector_type(4)));

__device__ __forceinline__ unsigned short f2b(float f) {
  unsigned u = __builtin_bit_cast(unsigned, f);
  unsigned r = (u + 0x7FFFu + ((u >> 16) & 1u)) >> 16;   // RNE
  return (unsigned short)r;
}

// ---------------- fp32 -> bf16 weight conversion ----------------
__global__ __launch_bounds__(256) void cvt_kernel(const float* __restrict__ src,
                                                  unsigned short* __restrict__ dst, int n4)
{
  int i = blockIdx.x * 256 + threadIdx.x;
  int stride = gridDim.x * 256;
  for (; i < n4; i += stride) {
    float4 v = ((const float4*)src)[i];
    ushort4 b;
    b.x = f2b(v.x); b.y = f2b(v.y); b.z = f2b(v.z); b.w = f2b(v.w);
    ((ushort4*)dst)[i] = b;
  }
}

// ---------------- Router (fp32, exact top-k match) ----------------
__global__ __launch_bounds__(256) void router_kernel(
    const float* __restrict__ x, const float* __restrict__ rw,
    int* __restrict__ counts, float* __restrict__ psum,
    int* __restrict__ etok, float* __restrict__ ewt)
{
  __shared__ float xs[32][DIM + 4];
  __shared__ float ws[NE][DIM + 4];
  __shared__ float lg[32][NE];
  __shared__ int hist[NE];
  __shared__ int base[NE];

  const int tid = threadIdx.x;
  const int t0 = blockIdx.x * 32;

  {
    const float4* xg = (const float4*)(x + (size_t)t0 * DIM);
    for (int i = tid; i < 32 * (DIM/4); i += 256) {
      int t = i / (DIM/4), c = i % (DIM/4);
      *(float4*)&xs[t][c*4] = xg[t*(DIM/4)+c];
    }
    const float4* wgp = (const float4*)rw;
    for (int i = tid; i < NE * (DIM/4); i += 256) {
      int e = i / (DIM/4), c = i % (DIM/4);
      *(float4*)&ws[e][c*4] = wgp[e*(DIM/4)+c];
    }
  }
  if (tid < NE) hist[tid] = 0;
  __syncthreads();

  for (int i = 0; i < 4; i++) {
    int idx = i*256 + tid;
    int t = idx >> 5, e = idx & 31;
    float acc = 0.f;
    for (int c = 0; c < DIM/4; c++) {
      float4 a = *(const float4*)&xs[t][c*4];
      float4 b = *(const float4*)&ws[e][c*4];
      acc += a.x*b.x + a.y*b.y + a.z*b.z + a.w*b.w;
    }
    lg[t][e] = acc;
  }
  __syncthreads();

  int ids[NK]; int slots[NK]; float wts[NK];
  if (tid < 32) {
    const int t = tid;
    float l[NE];
    #pragma unroll
    for (int e = 0; e < NE; e++) l[e] = lg[t][e];
    unsigned mask = 0;
    float vals[NK];
    #pragma unroll
    for (int k = 0; k < NK; k++) {
      float best = -INFINITY; int bi = 0;
      for (int e = 0; e < NE; e++)
        if (!((mask >> e) & 1u) && l[e] > best) { best = l[e]; bi = e; }
      mask |= 1u << bi; vals[k] = best; ids[k] = bi;
    }
    float s4 = 0.f;
    #pragma unroll
    for (int k = 0; k < NK; k++) { wts[k] = __expf(vals[k] - vals[0]); s4 += wts[k]; }
    #pragma unroll
    for (int k = 0; k < NK; k++) wts[k] /= s4;
    float s = 0.f;
    for (int e = 0; e < NE; e++) { l[e] = __expf(l[e] - vals[0]); s += l[e]; }
    float inv = 1.f / s;
    for (int e = 0; e < NE; e++) lg[t][e] = l[e] * inv;
    #pragma unroll
    for (int k = 0; k < NK; k++) slots[k] = atomicAdd(&hist[ids[k]], 1);
  }
  __syncthreads();
  if (tid < NE) {
    float s = 0.f;
    for (int t = 0; t < 32; t++) s += lg[t][tid];
    atomicAdd(&psum[tid], s);
    int h = hist[tid];
    base[tid] = h ? atomicAdd(&counts[tid], h) : 0;
  }
  __syncthreads();
  if (tid < 32) {
    #pragma unroll
    for (int k = 0; k < NK; k++) {
      int p = base[ids[k]] + slots[k];
      etok[(size_t)ids[k]*TOK + p] = t0 + tid;
      ewt [(size_t)ids[k]*TOK + p] = wts[k];
    }
  }
}

// ---------------- Aux loss ----------------
__global__ void aux_kernel(const int* __restrict__ counts,
                           const float* __restrict__ psum,
                           float* __restrict__ aux_out)
{
  int tid = threadIdx.x;
  float v = 0.f;
  if (tid < NE) v = (counts[tid] / (float)TOK) * (psum[tid] / (float)TOK);
  #pragma unroll
  for (int off = 32; off; off >>= 1) v += __shfl_down(v, off);
  if (tid == 0) aux_out[0] = (float)NE * v;
}

// ---------------- Expert FFN: bf16 MFMA, M=64 tiles, register A-frags ----------------
// 512 blocks, XCD-swizzled: expert e lives on XCD e%8 (4 experts/XCD -> L2-resident
// weight chunks). Block: 256 thr = 4 waves in 2x2 (token-half x f/d-half).
// Persistent loop over tile slots handles count imbalance.
__global__ __launch_bounds__(256, 2) void expert_mfma2_kernel(
    const float* __restrict__ x,
    const unsigned short* __restrict__ wgb,
    const unsigned short* __restrict__ wub,
    const unsigned short* __restrict__ wdb,
    const int* __restrict__ counts,
    const int* __restrict__ etok, const float* __restrict__ ewt,
    float* __restrict__ out)
{
  const int b    = blockIdx.x;
  const int i    = b >> 3;
  const int e    = (b & 7) + 8 * (i & 3);   // expert -> XCD b%8
  const int tile0 = i >> 2;                 // 0..15
  const int cnt  = counts[e];

  __shared__ __align__(16) unsigned short xs[64][DIM + 8];  // 33.8 KB
  __shared__ __align__(16) unsigned short hs[64][136];      // 17.4 KB
  __shared__ int   lel[64];
  __shared__ float lwt[64];

  const int tid  = threadIdx.x;
  const int lane = tid & 63;
  const int wv   = tid >> 6;
  const int mw   = wv & 1;     // token half (32 tokens)
  const int fw   = wv >> 1;    // f-half (64 f) / d-half (128 d)
  const int q    = lane >> 4;
  const int ln   = lane & 15;

  const int*   el = etok + (size_t)e * TOK;
  const float* ew = ewt  + (size_t)e * TOK;

  for (int t0 = tile0 * 64; t0 < cnt; t0 += 16 * 64) {
    if (tid < 64) {
      int gt = t0 + tid;
      lel[tid] = (gt < cnt) ? el[gt] : -1;
      lwt[tid] = (gt < cnt) ? ew[gt] : 0.f;
    }
    __syncthreads();
    {
      int row = tid >> 2, seg = tid & 3;
      int tok = lel[row];
      const float4* xg = (const float4*)(x + (size_t)(tok < 0 ? 0 : tok) * DIM);
      #pragma unroll
      for (int s = 0; s < 16; s++) {
        int c4 = seg + s * 4;
        float4 v = xg[c4];
        ushort4 bb;
        bb.x = f2b(v.x); bb.y = f2b(v.y); bb.z = f2b(v.z); bb.w = f2b(v.w);
        *(ushort4*)&xs[row][c4 * 4] = bb;
      }
    }
    __syncthreads();

    // A-fragments for this wave's 32 tokens, full K=256 (reused all chunks)
    bf16x8 xf[2][8];
    #pragma unroll
    for (int m = 0; m < 2; m++)
      #pragma unroll
      for (int k = 0; k < 8; k++)
        xf[m][k] = *(const bf16x8*)&xs[mw*32 + m*16 + ln][k*32 + q*8];

    f32x4 oacc[8][2];
    #pragma unroll
    for (int nt = 0; nt < 8; nt++) { oacc[nt][0] = (f32x4){0,0,0,0}; oacc[nt][1] = (f32x4){0,0,0,0}; }

    for (int ch = 0; ch < 8; ch++) {
      const int f0 = ch * 128;
      // ---- gate/up: wave covers f in [f0+fw*64, +64), tokens [mw*32, +32) ----
      f32x4 gacc[4][2], uacc[4][2];
      #pragma unroll
      for (int nt = 0; nt < 4; nt++) {
        gacc[nt][0] = (f32x4){0,0,0,0}; gacc[nt][1] = (f32x4){0,0,0,0};
        uacc[nt][0] = (f32x4){0,0,0,0}; uacc[nt][1] = (f32x4){0,0,0,0};
      }
      #pragma unroll
      for (int nt = 0; nt < 4; nt++) {
        const unsigned short* wgr = wgb + ((size_t)e*NF + f0 + fw*64 + nt*16 + ln) * DIM + q*8;
        const unsigned short* wur = wub + ((size_t)e*NF + f0 + fw*64 + nt*16 + ln) * DIM + q*8;
        #pragma unroll
        for (int k = 0; k < 8; k++) {
          bf16x8 bg = *(const bf16x8*)(wgr + k*32);
          bf16x8 bu = *(const bf16x8*)(wur + k*32);
          gacc[nt][0] = __builtin_amdgcn_mfma_f32_16x16x32_bf16(xf[0][k], bg, gacc[nt][0], 0,0,0);
          gacc[nt][1] = __builtin_amdgcn_mfma_f32_16x16x32_bf16(xf[1][k], bg, gacc[nt][1], 0,0,0);
          uacc[nt][0] = __builtin_amdgcn_mfma_f32_16x16x32_bf16(xf[0][k], bu, uacc[nt][0], 0,0,0);
          uacc[nt][1] = __builtin_amdgcn_mfma_f32_16x16x32_bf16(xf[1][k], bu, uacc[nt][1], 0,0,0);
        }
      }
      __syncthreads();   // previous chunk's hs fully consumed
      #pragma unroll
      for (int nt = 0; nt < 4; nt++)
        #pragma unroll
        for (int m = 0; m < 2; m++)
          #pragma unroll
          for (int r = 0; r < 4; r++) {
            float g = gacc[nt][m][r], u = uacc[nt][m][r];
            float h = (g / (1.f + __expf(-g))) * u;   // silu(g)*u
            hs[mw*32 + m*16 + q*4 + r][fw*64 + nt*16 + ln] = f2b(h);
          }
      __syncthreads();
      // ---- down: wave covers d in [fw*128, +128), tokens [mw*32, +32) ----
      #pragma unroll
      for (int kk = 0; kk < 4; kk++) {
        bf16x8 af0 = *(const bf16x8*)&hs[mw*32      + ln][kk*32 + q*8];
        bf16x8 af1 = *(const bf16x8*)&hs[mw*32 + 16 + ln][kk*32 + q*8];
        #pragma unroll
        for (int nt = 0; nt < 8; nt++) {
          const unsigned short* wdr =
              wdb + ((size_t)e*DIM + fw*128 + nt*16 + ln) * NF + f0 + kk*32 + q*8;
          bf16x8 bd = *(const bf16x8*)wdr;
          oacc[nt][0] = __builtin_amdgcn_mfma_f32_16x16x32_bf16(af0, bd, oacc[nt][0], 0,0,0);
          oacc[nt][1] = __builtin_amdgcn_mfma_f32_16x16x32_bf16(af1, bd, oacc[nt][1], 0,0,0);
        }
      }
    }

    // epilogue: weighted atomic scatter
    #pragma unroll
    for (int nt = 0; nt < 8; nt++) {
      int d = fw*128 + nt*16 + ln;
      #pragma unroll
      for (int m = 0; m < 2; m++)
        #pragma unroll
        for (int r = 0; r < 4; r++) {
          int tl = mw*32 + m*16 + q*4 + r;
          int tok = lel[tl];
          if (tok >= 0)
            atomicAdd(&out[(size_t)tok*DIM + d], lwt[tl] * oacc[nt][m][r]);
        }
    }
    __syncthreads();   // lel/lwt reused next tile iteration
  }
}

extern "C" void kernel_launch(void* const* d_in, const int* in_sizes, int n_in,
                              void* d_out, int out_size, void* d_ws, size_t ws_size,
                              hipStream_t stream)
{
  const float* x  = (const float*)d_in[0];
  const float* rw = (const float*)d_in[1];
  const float* wg = (const float*)d_in[2];
  const float* wu = (const float*)d_in[3];
  const float* wd = (const float*)d_in[4];
  float* out = (float*)d_out;

  const size_t W = (size_t)NE * NF * DIM;   // elems per weight tensor
  int*   counts = (int*)d_ws;
  float* psum   = (float*)((char*)d_ws + 128);
  int*   etok   = (int*)((char*)d_ws + 256);
  float* ewt    = (float*)((char*)d_ws + 256 + (size_t)NE*TOK*4);
  unsigned short* wgb = (unsigned short*)((char*)d_ws + 256 + (size_t)NE*TOK*8);
  unsigned short* wub = wgb + W;
  unsigned short* wdb = wub + W;

  hipMemsetAsync(d_ws, 0, 256, stream);
  hipMemsetAsync(d_out, 0, (size_t)out_size * 4, stream);

  router_kernel<<<TOK/32, 256, 0, stream>>>(x, rw, counts, psum, etok, ewt);

  const int n4 = (int)(W / 4);
  cvt_kernel<<<2048, 256, 0, stream>>>(wg, wgb, n4);
  cvt_kernel<<<2048, 256, 0, stream>>>(wu, wub, n4);
  cvt_kernel<<<2048, 256, 0, stream>>>(wd, wdb, n4);

  aux_kernel<<<1, 64, 0, stream>>>(counts, psum, out + (size_t)TOK*DIM);

  expert_mfma2_kernel<<<512, 256, 0, stream>>>(
      x, wgb, wub, wdb, counts, etok, ewt, out);
}

// Round 4
// 451.925 us; speedup vs baseline: 8.1766x; 1.2045x over previous
//
#include <hip/hip_runtime.h>
#include <math.h>

#define TOK 8192   // B*S tokens
#define DIM 256    // hidden
#define NE  32     // experts
#define NK  4      // top-k
#define NF  1024   // ffn dim

typedef __bf16 bf16x8 __attribute__((ext_vector_type(8)));
typedef float  f32x4  __attribute__((ext_vector_type(4)));

__device__ __forceinline__ unsigned short f2b(float f) {
  unsigned u = __builtin_bit_cast(unsigned, f);
  unsigned r = (u + 0x7FFFu + ((u >> 16) & 1u)) >> 16;   // RNE
  return (unsigned short)r;
}

// async global->LDS, 16B per lane (global_load_lds_dwordx4)
__device__ __forceinline__ void gload_lds16(const void* g, void* l) {
  __builtin_amdgcn_global_load_lds(
      (const __attribute__((address_space(1))) unsigned int*)g,
      (__attribute__((address_space(3))) unsigned int*)l, 16, 0, 0);
}

// ---------------- fused fp32 -> bf16 weight conversion ----------------
// sections: 0 = wg (plain), 1 = wu (plain), 2 = wd (permute to [e][ch16][d256][f64])
__global__ __launch_bounds__(256) void cvt_all_kernel(
    const float* __restrict__ wg, const float* __restrict__ wu,
    const float* __restrict__ wd,
    unsigned short* __restrict__ wgb, unsigned short* __restrict__ wub,
    unsigned short* __restrict__ wdt)
{
  const int n4 = (int)((size_t)NE * NF * DIM / 4);   // 2,097,152 ushort4s
  const int sec = blockIdx.x >> 11;
  const int stride = 2048 * 256;
  int i = (blockIdx.x & 2047) * 256 + threadIdx.x;
  if (sec == 0) {
    for (; i < n4; i += stride) {
      float4 v = ((const float4*)wg)[i];
      ((ushort4*)wgb)[i] = make_ushort4(f2b(v.x), f2b(v.y), f2b(v.z), f2b(v.w));
    }
  } else if (sec == 1) {
    for (; i < n4; i += stride) {
      float4 v = ((const float4*)wu)[i];
      ((ushort4*)wub)[i] = make_ushort4(f2b(v.x), f2b(v.y), f2b(v.z), f2b(v.w));
    }
  } else {
    for (; i < n4; i += stride) {
      // dst ushort idx j=i*4 : j = ((e*16+ch)*256 + d)*64 + fi
      int fi4 = i & 15;
      int d   = (i >> 4) & 255;
      int ch  = (i >> 12) & 15;
      int e   = i >> 16;
      int s4  = (e * 256 + d) * 256 + ch * 16 + fi4;  // src float4 idx
      float4 v = ((const float4*)wd)[s4];
      ((ushort4*)wdt)[i] = make_ushort4(f2b(v.x), f2b(v.y), f2b(v.z), f2b(v.w));
    }
  }
}

// ---------------- Router (fp32, exact top-k match) ----------------
__global__ __launch_bounds__(256) void router_kernel(
    const float* __restrict__ x, const float* __restrict__ rw,
    int* __restrict__ counts, float* __restrict__ psum,
    int* __restrict__ etok, float* __restrict__ ewt)
{
  __shared__ float xs[32][DIM + 4];
  __shared__ float ws[NE][DIM + 4];
  __shared__ float lg[32][NE];
  __shared__ int hist[NE];
  __shared__ int base[NE];

  const int tid = threadIdx.x;
  const int t0 = blockIdx.x * 32;

  {
    const float4* xg = (const float4*)(x + (size_t)t0 * DIM);
    for (int i = tid; i < 32 * (DIM/4); i += 256) {
      int t = i / (DIM/4), c = i % (DIM/4);
      *(float4*)&xs[t][c*4] = xg[t*(DIM/4)+c];
    }
    const float4* wgp = (const float4*)rw;
    for (int i = tid; i < NE * (DIM/4); i += 256) {
      int e = i / (DIM/4), c = i % (DIM/4);
      *(float4*)&ws[e][c*4] = wgp[e*(DIM/4)+c];
    }
  }
  if (tid < NE) hist[tid] = 0;
  __syncthreads();

  for (int i = 0; i < 4; i++) {
    int idx = i*256 + tid;
    int t = idx >> 5, e = idx & 31;
    float acc = 0.f;
    for (int c = 0; c < DIM/4; c++) {
      float4 a = *(const float4*)&xs[t][c*4];
      float4 b = *(const float4*)&ws[e][c*4];
      acc += a.x*b.x + a.y*b.y + a.z*b.z + a.w*b.w;
    }
    lg[t][e] = acc;
  }
  __syncthreads();

  int ids[NK]; int slots[NK]; float wts[NK];
  if (tid < 32) {
    const int t = tid;
    float l[NE];
    #pragma unroll
    for (int e = 0; e < NE; e++) l[e] = lg[t][e];
    unsigned mask = 0;
    float vals[NK];
    #pragma unroll
    for (int k = 0; k < NK; k++) {
      float best = -INFINITY; int bi = 0;
      for (int e = 0; e < NE; e++)
        if (!((mask >> e) & 1u) && l[e] > best) { best = l[e]; bi = e; }
      mask |= 1u << bi; vals[k] = best; ids[k] = bi;
    }
    float s4 = 0.f;
    #pragma unroll
    for (int k = 0; k < NK; k++) { wts[k] = __expf(vals[k] - vals[0]); s4 += wts[k]; }
    #pragma unroll
    for (int k = 0; k < NK; k++) wts[k] /= s4;
    float s = 0.f;
    for (int e = 0; e < NE; e++) { l[e] = __expf(l[e] - vals[0]); s += l[e]; }
    float inv = 1.f / s;
    for (int e = 0; e < NE; e++) lg[t][e] = l[e] * inv;
    #pragma unroll
    for (int k = 0; k < NK; k++) slots[k] = atomicAdd(&hist[ids[k]], 1);
  }
  __syncthreads();
  if (tid < NE) {
    float s = 0.f;
    for (int t = 0; t < 32; t++) s += lg[t][tid];
    atomicAdd(&psum[tid], s);
    int h = hist[tid];
    base[tid] = h ? atomicAdd(&counts[tid], h) : 0;
  }
  __syncthreads();
  if (tid < 32) {
    #pragma unroll
    for (int k = 0; k < NK; k++) {
      int p = base[ids[k]] + slots[k];
      etok[(size_t)ids[k]*TOK + p] = t0 + tid;
      ewt [(size_t)ids[k]*TOK + p] = wts[k];
    }
  }
}

// ---------------- Aux loss ----------------
__global__ void aux_kernel(const int* __restrict__ counts,
                           const float* __restrict__ psum,
                           float* __restrict__ aux_out)
{
  int tid = threadIdx.x;
  float v = 0.f;
  if (tid < NE) v = (counts[tid] / (float)TOK) * (psum[tid] / (float)TOK);
  #pragma unroll
  for (int off = 32; off; off >>= 1) v += __shfl_down(v, off);
  if (tid == 0) aux_out[0] = (float)NE * v;
}

// ---------------- Expert FFN: M=128 tiles, LDS-staged weights ----------------
// 256 blocks x 512 threads (8 waves). Block = (expert e, slot s): tokens
// s*128 + n*1024 of expert e's list. XCD-pinned: expert e -> XCD e%8.
// Waves: mw = wv&3 (32-token quarter), nw = wv>>2 (f/d half).
// Per 64-f chunk: stage Wg(32KB) -> MFMA, stage Wu -> MFMA, silu->hs,
// stage Wd chunk(32KB, pre-permuted contiguous) -> down MFMA (acc in regs).
__global__ __launch_bounds__(512, 2) void expert_mfma3_kernel(
    const float* __restrict__ x,
    const unsigned short* __restrict__ wgb,
    const unsigned short* __restrict__ wub,
    const unsigned short* __restrict__ wdt,
    const int* __restrict__ counts,
    const int* __restrict__ etok, const float* __restrict__ ewt,
    float* __restrict__ out)
{
  const int b  = blockIdx.x;
  const int j  = b >> 3;
  const int e  = (b & 7) + 8 * (j & 3);   // expert -> XCD b%8
  const int s0 = j >> 2;                  // slot 0..7
  const int cnt = counts[e];

  __shared__ unsigned short stg[16384];     // 32KB staging buffer
  __shared__ unsigned short hs[128][72];    // 18KB bf16 H chunk (padded)
  __shared__ int   lel[128];
  __shared__ float lwt[128];

  const int tid  = threadIdx.x;
  const int lane = tid & 63;
  const int wv   = tid >> 6;
  const int mw   = wv & 3;      // token quarter (32 tokens)
  const int nw   = wv >> 2;     // 0/1: f-half within chunk, d-half for down
  const int q    = lane >> 4;
  const int ln   = lane & 15;

  const int*   el = etok + (size_t)e * TOK;
  const float* ew = ewt  + (size_t)e * TOK;

  for (int t0 = s0 * 128; t0 < cnt; t0 += 1024) {
    if (tid < 128) {
      int gt = t0 + tid;
      lel[tid] = (gt < cnt) ? el[gt] : -1;
      lwt[tid] = (gt < cnt) ? ew[gt] : 0.f;
    }
    __syncthreads();

    // A-fragments: 32 tokens x K=256, straight from global (fp32->bf16)
    bf16x8 xf[2][8];
    #pragma unroll
    for (int m = 0; m < 2; m++) {
      int row = mw*32 + m*16 + ln;
      int tok = lel[row]; if (tok < 0) tok = 0;
      const float* xr = x + (size_t)tok * DIM;
      #pragma unroll
      for (int k = 0; k < 8; k++) {
        float4 a = *(const float4*)(xr + k*32 + q*8);
        float4 c = *(const float4*)(xr + k*32 + q*8 + 4);
        union { bf16x8 v; unsigned short s[8]; } t;
        t.s[0]=f2b(a.x); t.s[1]=f2b(a.y); t.s[2]=f2b(a.z); t.s[3]=f2b(a.w);
        t.s[4]=f2b(c.x); t.s[5]=f2b(c.y); t.s[6]=f2b(c.z); t.s[7]=f2b(c.w);
        xf[m][k] = t.v;
      }
    }

    f32x4 oacc[8][2];
    #pragma unroll
    for (int nt = 0; nt < 8; nt++) { oacc[nt][0] = (f32x4){0,0,0,0}; oacc[nt][1] = (f32x4){0,0,0,0}; }

    for (int ch = 0; ch < 16; ch++) {
      const int f0 = ch * 64;
      f32x4 ga[2][2], ua[2][2];

      // ---- stage Wg rows [f0, f0+64) x K=256 (32KB contiguous) ----
      __syncthreads();   // stg free
      {
        const char* src = (const char*)(wgb + ((size_t)e*NF + f0) * DIM);
        #pragma unroll
        for (int r = 0; r < 4; r++)
          gload_lds16(src + tid*16 + r*8192, (char*)stg + tid*16 + r*8192);
      }
      __syncthreads();   // staged (barrier drains vmcnt)
      #pragma unroll
      for (int nt = 0; nt < 2; nt++) {
        ga[nt][0] = (f32x4){0,0,0,0}; ga[nt][1] = (f32x4){0,0,0,0};
        #pragma unroll
        for (int k = 0; k < 8; k++) {
          bf16x8 bg = *(const bf16x8*)&stg[(nw*32 + nt*16 + ln)*256 + k*32 + q*8];
          ga[nt][0] = __builtin_amdgcn_mfma_f32_16x16x32_bf16(xf[0][k], bg, ga[nt][0], 0,0,0);
          ga[nt][1] = __builtin_amdgcn_mfma_f32_16x16x32_bf16(xf[1][k], bg, ga[nt][1], 0,0,0);
        }
      }

      // ---- stage Wu, same rows ----
      __syncthreads();
      {
        const char* src = (const char*)(wub + ((size_t)e*NF + f0) * DIM);
        #pragma unroll
        for (int r = 0; r < 4; r++)
          gload_lds16(src + tid*16 + r*8192, (char*)stg + tid*16 + r*8192);
      }
      __syncthreads();
      #pragma unroll
      for (int nt = 0; nt < 2; nt++) {
        ua[nt][0] = (f32x4){0,0,0,0}; ua[nt][1] = (f32x4){0,0,0,0};
        #pragma unroll
        for (int k = 0; k < 8; k++) {
          bf16x8 bu = *(const bf16x8*)&stg[(nw*32 + nt*16 + ln)*256 + k*32 + q*8];
          ua[nt][0] = __builtin_amdgcn_mfma_f32_16x16x32_bf16(xf[0][k], bu, ua[nt][0], 0,0,0);
          ua[nt][1] = __builtin_amdgcn_mfma_f32_16x16x32_bf16(xf[1][k], bu, ua[nt][1], 0,0,0);
        }
      }
      // silu(g)*u -> hs  (cols = f-local 0..63)
      #pragma unroll
      for (int nt = 0; nt < 2; nt++)
        #pragma unroll
        for (int m = 0; m < 2; m++)
          #pragma unroll
          for (int r = 0; r < 4; r++) {
            float g = ga[nt][m][r], u = ua[nt][m][r];
            hs[mw*32 + m*16 + q*4 + r][nw*32 + nt*16 + ln] =
                f2b((g / (1.f + __expf(-g))) * u);
          }

      // ---- stage Wd chunk [256 d][64 f] (32KB, pre-permuted) ----
      __syncthreads();   // stg consumed + hs complete
      {
        const char* src = (const char*)(wdt + (((size_t)e*16 + ch) << 14));
        #pragma unroll
        for (int r = 0; r < 4; r++)
          gload_lds16(src + tid*16 + r*8192, (char*)stg + tid*16 + r*8192);
      }
      __syncthreads();
      // ---- down: wave covers d in [nw*128, +128), K-slice = this chunk's 64 f ----
      #pragma unroll
      for (int kk = 0; kk < 2; kk++) {
        bf16x8 af0 = *(const bf16x8*)&hs[mw*32      + ln][kk*32 + q*8];
        bf16x8 af1 = *(const bf16x8*)&hs[mw*32 + 16 + ln][kk*32 + q*8];
        #pragma unroll
        for (int nt = 0; nt < 8; nt++) {
          bf16x8 bd = *(const bf16x8*)&stg[(nw*128 + nt*16 + ln)*64 + kk*32 + q*8];
          oacc[nt][0] = __builtin_amdgcn_mfma_f32_16x16x32_bf16(af0, bd, oacc[nt][0], 0,0,0);
          oacc[nt][1] = __builtin_amdgcn_mfma_f32_16x16x32_bf16(af1, bd, oacc[nt][1], 0,0,0);
        }
      }
    }

    // epilogue: weighted atomic scatter
    #pragma unroll
    for (int nt = 0; nt < 8; nt++) {
      int d = nw*128 + nt*16 + ln;
      #pragma unroll
      for (int m = 0; m < 2; m++)
        #pragma unroll
        for (int r = 0; r < 4; r++) {
          int tl = mw*32 + m*16 + q*4 + r;
          int tok = lel[tl];
          if (tok >= 0)
            atomicAdd(&out[(size_t)tok*DIM + d], lwt[tl] * oacc[nt][m][r]);
        }
    }
    __syncthreads();   // protect lel/lwt (and stg) before next tile
  }
}

extern "C" void kernel_launch(void* const* d_in, const int* in_sizes, int n_in,
                              void* d_out, int out_size, void* d_ws, size_t ws_size,
                              hipStream_t stream)
{
  const float* x  = (const float*)d_in[0];
  const float* rw = (const float*)d_in[1];
  const float* wg = (const float*)d_in[2];
  const float* wu = (const float*)d_in[3];
  const float* wd = (const float*)d_in[4];
  float* out = (float*)d_out;

  const size_t W = (size_t)NE * NF * DIM;   // elems per weight tensor
  int*   counts = (int*)d_ws;
  float* psum   = (float*)((char*)d_ws + 128);
  int*   etok   = (int*)((char*)d_ws + 256);
  float* ewt    = (float*)((char*)d_ws + 256 + (size_t)NE*TOK*4);
  unsigned short* wgb = (unsigned short*)((char*)d_ws + 256 + (size_t)NE*TOK*8);
  unsigned short* wub = wgb + W;
  unsigned short* wdt = wub + W;

  hipMemsetAsync(d_ws, 0, 256, stream);
  hipMemsetAsync(d_out, 0, (size_t)out_size * 4, stream);

  router_kernel<<<TOK/32, 256, 0, stream>>>(x, rw, counts, psum, etok, ewt);
  cvt_all_kernel<<<3*2048, 256, 0, stream>>>(wg, wu, wd, wgb, wub, wdt);
  aux_kernel<<<1, 64, 0, stream>>>(counts, psum, out + (size_t)TOK*DIM);

  expert_mfma3_kernel<<<256, 512, 0, stream>>>(
      x, wgb, wub, wdt, counts, etok, ewt, out);
}

// Round 5
// 441.471 us; speedup vs baseline: 8.3702x; 1.0237x over previous
//
#include <hip/hip_runtime.h>
#include <math.h>

#define TOK 8192   // B*S tokens
#define DIM 256    // hidden
#define NE  32     // experts
#define NK  4      // top-k
#define NF  1024   // ffn dim

typedef __bf16 bf16x8 __attribute__((ext_vector_type(8)));
typedef float  f32x4  __attribute__((ext_vector_type(4)));

__device__ __forceinline__ unsigned short f2b(float f) {
  unsigned u = __builtin_bit_cast(unsigned, f);
  unsigned r = (u + 0x7FFFu + ((u >> 16) & 1u)) >> 16;   // RNE
  return (unsigned short)r;
}

// async global->LDS, 16B per lane (global_load_lds_dwordx4)
__device__ __forceinline__ void gload_lds16(const void* g, void* l) {
  __builtin_amdgcn_global_load_lds(
      (const __attribute__((address_space(1))) unsigned int*)g,
      (__attribute__((address_space(3))) unsigned int*)l, 16, 0, 0);
}

// ================= fused router + weight-convert =================
// blocks [0,256): router (32 tokens each). blocks [256, 256+3*2048): cvt.
// Gate/up bf16 layout (XOR-swizzled, conflict-free LDS frag reads):
//   ushort (e*NF+f)*256 + ((g ^ (f&7))<<3) + (k&7),  g = k>>3
// Down bf16 layout: per (e,ch): [256 d][32 f]:
//   ushort ((e*32+ch)*256 + d)*32 + ((q ^ (d&3))<<3) + (fi&7),  q = fi>>3
__global__ __launch_bounds__(256) void router_cvt_kernel(
    const float* __restrict__ x, const float* __restrict__ rw,
    const float* __restrict__ wg, const float* __restrict__ wu,
    const float* __restrict__ wd,
    int* __restrict__ counts, float* __restrict__ psum,
    int* __restrict__ etok, float* __restrict__ ewt,
    unsigned short* __restrict__ wgp, unsigned short* __restrict__ wup,
    unsigned short* __restrict__ wdp)
{
  __shared__ float xs[32][DIM + 4];
  __shared__ float ws[NE][DIM + 4];
  __shared__ float lg[32][NE];
  __shared__ int hist[NE];
  __shared__ int base[NE];

  const int tid = threadIdx.x;

  if (blockIdx.x >= 256) {
    // ---------- cvt branch ----------
    const int b2 = blockIdx.x - 256;
    const int sec = b2 >> 11;
    const int n4 = (int)((size_t)NE * NF * DIM / 4);
    const int stride = 2048 * 256;
    int i = (b2 & 2047) * 256 + tid;
    if (sec < 2) {
      const float* src = sec ? wu : wg;
      unsigned short* dst = sec ? wup : wgp;
      for (; i < n4; i += stride) {
        int k4 = i & 63, row = i >> 6;          // row = e*NF+f; row&7 == f&7
        int p = (k4 >> 1) ^ (row & 7);
        float4 v = ((const float4*)src)[i];
        ((ushort4*)dst)[((size_t)row << 6) + (p << 1) + (k4 & 1)] =
            make_ushort4(f2b(v.x), f2b(v.y), f2b(v.z), f2b(v.w));
      }
    } else {
      for (; i < n4; i += stride) {
        int fi4 = i & 7, d = (i >> 3) & 255, ch = (i >> 11) & 31, e = i >> 16;
        int s4 = (e * 256 + d) * 256 + ch * 8 + fi4;
        int p = (fi4 >> 1) ^ (d & 3);
        float4 v = ((const float4*)wd)[s4];
        ((ushort4*)wdp)[(size_t)(((e * 32 + ch) * 256 + d) * 8) + p * 2 + (fi4 & 1)] =
            make_ushort4(f2b(v.x), f2b(v.y), f2b(v.z), f2b(v.w));
      }
    }
    return;
  }

  // ---------- router branch ----------
  const int t0 = blockIdx.x * 32;
  {
    const float4* xg = (const float4*)(x + (size_t)t0 * DIM);
    for (int i = tid; i < 32 * (DIM/4); i += 256) {
      int t = i / (DIM/4), c = i % (DIM/4);
      *(float4*)&xs[t][c*4] = xg[t*(DIM/4)+c];
    }
    const float4* wgq = (const float4*)rw;
    for (int i = tid; i < NE * (DIM/4); i += 256) {
      int e = i / (DIM/4), c = i % (DIM/4);
      *(float4*)&ws[e][c*4] = wgq[e*(DIM/4)+c];
    }
  }
  if (tid < NE) hist[tid] = 0;
  __syncthreads();

  for (int i = 0; i < 4; i++) {
    int idx = i*256 + tid;
    int t = idx >> 5, e = idx & 31;
    float acc = 0.f;
    for (int c = 0; c < DIM/4; c++) {
      float4 a = *(const float4*)&xs[t][c*4];
      float4 b = *(const float4*)&ws[e][c*4];
      acc += a.x*b.x + a.y*b.y + a.z*b.z + a.w*b.w;
    }
    lg[t][e] = acc;
  }
  __syncthreads();

  int ids[NK]; int slots[NK]; float wts[NK];
  if (tid < 32) {
    const int t = tid;
    float l[NE];
    #pragma unroll
    for (int e = 0; e < NE; e++) l[e] = lg[t][e];
    unsigned mask = 0;
    float vals[NK];
    #pragma unroll
    for (int k = 0; k < NK; k++) {
      float best = -INFINITY; int bi = 0;
      for (int e = 0; e < NE; e++)
        if (!((mask >> e) & 1u) && l[e] > best) { best = l[e]; bi = e; }
      mask |= 1u << bi; vals[k] = best; ids[k] = bi;
    }
    float s4 = 0.f;
    #pragma unroll
    for (int k = 0; k < NK; k++) { wts[k] = __expf(vals[k] - vals[0]); s4 += wts[k]; }
    #pragma unroll
    for (int k = 0; k < NK; k++) wts[k] /= s4;
    float s = 0.f;
    for (int e = 0; e < NE; e++) { l[e] = __expf(l[e] - vals[0]); s += l[e]; }
    float inv = 1.f / s;
    for (int e = 0; e < NE; e++) lg[t][e] = l[e] * inv;
    #pragma unroll
    for (int k = 0; k < NK; k++) slots[k] = atomicAdd(&hist[ids[k]], 1);
  }
  __syncthreads();
  if (tid < NE) {
    float s = 0.f;
    for (int t = 0; t < 32; t++) s += lg[t][tid];
    atomicAdd(&psum[tid], s);
    int h = hist[tid];
    base[tid] = h ? atomicAdd(&counts[tid], h) : 0;
  }
  __syncthreads();
  if (tid < 32) {
    #pragma unroll
    for (int k = 0; k < NK; k++) {
      int p = base[ids[k]] + slots[k];
      etok[(size_t)ids[k]*TOK + p] = t0 + tid;
      ewt [(size_t)ids[k]*TOK + p] = wts[k];
    }
  }
}

// ---------------- Aux loss ----------------
__global__ void aux_kernel(const int* __restrict__ counts,
                           const float* __restrict__ psum,
                           float* __restrict__ aux_out)
{
  int tid = threadIdx.x;
  float v = 0.f;
  if (tid < NE) v = (counts[tid] / (float)TOK) * (psum[tid] / (float)TOK);
  #pragma unroll
  for (int off = 32; off; off >>= 1) v += __shfl_down(v, off);
  if (tid == 0) aux_out[0] = (float)NE * v;
}

// ============ Expert FFN: pipelined LDS staging, swizzled, M=128 ============
// 256 blocks x 512 thr (8 waves: mw=wv&3 token-quarter, nw=wv>>2 f/d half).
// 32-f chunks; steps G,U,D per chunk; double-buffered 16KB stages with
// prefetch issued right after each barrier (loads fly during compute).
__global__ __launch_bounds__(512, 2) void expert_mfma4_kernel(
    const float* __restrict__ x,
    const unsigned short* __restrict__ wgp,
    const unsigned short* __restrict__ wup,
    const unsigned short* __restrict__ wdp,
    const int* __restrict__ counts,
    const int* __restrict__ etok, const float* __restrict__ ewt,
    float* __restrict__ out)
{
  const int b  = blockIdx.x;
  const int j  = b >> 3;
  const int e  = (b & 7) + 8 * (j & 3);   // expert -> XCD b%8
  const int s0 = j >> 2;                  // slot 0..7
  const int cnt = counts[e];

  __shared__ unsigned short stg[2][8192];   // 2 x 16KB
  __shared__ unsigned short hs[128][40];    // 10KB (32 used + 8 pad)
  __shared__ int   lel[128];
  __shared__ float lwt[128];

  const int tid  = threadIdx.x;
  const int lane = tid & 63;
  const int wv   = tid >> 6;
  const int mw   = wv & 3;      // token quarter (32 tokens)
  const int nw   = wv >> 2;     // f-half (16 f) / d-half (128 d)
  const int q    = lane >> 4;
  const int ln   = lane & 15;

  const unsigned short* wgE = wgp + (size_t)e * NF * 256;
  const unsigned short* wuE = wup + (size_t)e * NF * 256;
  const unsigned short* wdE = wdp + (size_t)e * 32 * 8192;

  const int*   el = etok + (size_t)e * TOK;
  const float* ew = ewt  + (size_t)e * TOK;

  for (int t0 = s0 * 128; t0 < cnt; t0 += 1024) {
    if (tid < 128) {
      int gt = t0 + tid;
      lel[tid] = (gt < cnt) ? el[gt] : -1;
      lwt[tid] = (gt < cnt) ? ew[gt] : 0.f;
    }
    __syncthreads();

    // A-fragments: 32 tokens x K=256 in registers (fp32->bf16)
    bf16x8 xf[2][8];
    #pragma unroll
    for (int m = 0; m < 2; m++) {
      int row = mw*32 + m*16 + ln;
      int tok = lel[row]; if (tok < 0) tok = 0;
      const float* xr = x + (size_t)tok * DIM;
      #pragma unroll
      for (int k = 0; k < 8; k++) {
        float4 a = *(const float4*)(xr + k*32 + q*8);
        float4 c = *(const float4*)(xr + k*32 + q*8 + 4);
        union { bf16x8 v; unsigned short s[8]; } t;
        t.s[0]=f2b(a.x); t.s[1]=f2b(a.y); t.s[2]=f2b(a.z); t.s[3]=f2b(a.w);
        t.s[4]=f2b(c.x); t.s[5]=f2b(c.y); t.s[6]=f2b(c.z); t.s[7]=f2b(c.w);
        xf[m][k] = t.v;
      }
    }

    f32x4 oacc[8][2];
    #pragma unroll
    for (int nt = 0; nt < 8; nt++) { oacc[nt][0] = (f32x4){0,0,0,0}; oacc[nt][1] = (f32x4){0,0,0,0}; }

    // prologue: stage G(0) into stg[0]
    {
      const char* src = (const char*)wgE;
      char* dst = (char*)stg[0];
      gload_lds16(src + tid*16, dst + tid*16);
      gload_lds16(src + tid*16 + 8192, dst + tid*16 + 8192);
    }

    int buf = 0;
    f32x4 ga0, ga1;
    const int grow = (nw*16 + ln) * 256;   // gate/up frag row base (ushorts)
    const int rx   = ln & 7;               // gate/up XOR key
    const int dx   = ln & 3;               // down XOR key

    for (int ch = 0; ch < 32; ch++) {
      // ================= G phase =================
      __syncthreads();                       // G(ch) staged; other buf free
      { // prefetch U(ch)
        const char* src = (const char*)(wuE + ch*8192);
        char* dst = (char*)stg[buf ^ 1];
        gload_lds16(src + tid*16, dst + tid*16);
        gload_lds16(src + tid*16 + 8192, dst + tid*16 + 8192);
      }
      {
        const unsigned short* S = stg[buf];
        ga0 = (f32x4){0,0,0,0}; ga1 = (f32x4){0,0,0,0};
        #pragma unroll
        for (int k = 0; k < 8; k++) {
          bf16x8 bg = *(const bf16x8*)&S[grow + (((k*4 + q) ^ rx) << 3)];
          ga0 = __builtin_amdgcn_mfma_f32_16x16x32_bf16(xf[0][k], bg, ga0, 0,0,0);
          ga1 = __builtin_amdgcn_mfma_f32_16x16x32_bf16(xf[1][k], bg, ga1, 0,0,0);
        }
      }
      buf ^= 1;
      // ================= U phase =================
      __syncthreads();                       // U(ch) staged
      { // prefetch D(ch)
        const char* src = (const char*)(wdE + ch*8192);
        char* dst = (char*)stg[buf ^ 1];
        gload_lds16(src + tid*16, dst + tid*16);
        gload_lds16(src + tid*16 + 8192, dst + tid*16 + 8192);
      }
      {
        const unsigned short* S = stg[buf];
        f32x4 ua0 = (f32x4){0,0,0,0}, ua1 = (f32x4){0,0,0,0};
        #pragma unroll
        for (int k = 0; k < 8; k++) {
          bf16x8 bu = *(const bf16x8*)&S[grow + (((k*4 + q) ^ rx) << 3)];
          ua0 = __builtin_amdgcn_mfma_f32_16x16x32_bf16(xf[0][k], bu, ua0, 0,0,0);
          ua1 = __builtin_amdgcn_mfma_f32_16x16x32_bf16(xf[1][k], bu, ua1, 0,0,0);
        }
        #pragma unroll
        for (int r = 0; r < 4; r++) {
          float g0 = ga0[r], g1 = ga1[r];
          hs[mw*32      + q*4 + r][nw*16 + ln] = f2b((g0 / (1.f + __expf(-g0))) * ua0[r]);
          hs[mw*32 + 16 + q*4 + r][nw*16 + ln] = f2b((g1 / (1.f + __expf(-g1))) * ua1[r]);
        }
      }
      buf ^= 1;
      // ================= D phase =================
      __syncthreads();                       // D(ch) staged + hs complete
      if (ch + 1 < 32) { // prefetch G(ch+1)
        const char* src = (const char*)(wgE + (ch+1)*8192);
        char* dst = (char*)stg[buf ^ 1];
        gload_lds16(src + tid*16, dst + tid*16);
        gload_lds16(src + tid*16 + 8192, dst + tid*16 + 8192);
      }
      {
        const unsigned short* S = stg[buf];
        bf16x8 af0 = *(const bf16x8*)&hs[mw*32      + ln][q*8];
        bf16x8 af1 = *(const bf16x8*)&hs[mw*32 + 16 + ln][q*8];
        #pragma unroll
        for (int nt = 0; nt < 8; nt++) {
          int dd = nw*128 + nt*16 + ln;
          bf16x8 bd = *(const bf16x8*)&S[dd*32 + ((q ^ dx) << 3)];
          oacc[nt][0] = __builtin_amdgcn_mfma_f32_16x16x32_bf16(af0, bd, oacc[nt][0], 0,0,0);
          oacc[nt][1] = __builtin_amdgcn_mfma_f32_16x16x32_bf16(af1, bd, oacc[nt][1], 0,0,0);
        }
      }
      buf ^= 1;
    }

    // epilogue: weighted atomic scatter
    #pragma unroll
    for (int nt = 0; nt < 8; nt++) {
      int d = nw*128 + nt*16 + ln;
      #pragma unroll
      for (int m = 0; m < 2; m++)
        #pragma unroll
        for (int r = 0; r < 4; r++) {
          int tl = mw*32 + m*16 + q*4 + r;
          int tok = lel[tl];
          if (tok >= 0)
            atomicAdd(&out[(size_t)tok*DIM + d], lwt[tl] * oacc[nt][m][r]);
        }
    }
    __syncthreads();   // protect lel/lwt/stg before next tile
  }
}

extern "C" void kernel_launch(void* const* d_in, const int* in_sizes, int n_in,
                              void* d_out, int out_size, void* d_ws, size_t ws_size,
                              hipStream_t stream)
{
  const float* x  = (const float*)d_in[0];
  const float* rw = (const float*)d_in[1];
  const float* wg = (const float*)d_in[2];
  const float* wu = (const float*)d_in[3];
  const float* wd = (const float*)d_in[4];
  float* out = (float*)d_out;

  const size_t W = (size_t)NE * NF * DIM;   // elems per weight tensor
  int*   counts = (int*)d_ws;
  float* psum   = (float*)((char*)d_ws + 128);
  int*   etok   = (int*)((char*)d_ws + 256);
  float* ewt    = (float*)((char*)d_ws + 256 + (size_t)NE*TOK*4);
  unsigned short* wgp = (unsigned short*)((char*)d_ws + 256 + (size_t)NE*TOK*8);
  unsigned short* wup = wgp + W;
  unsigned short* wdp = wup + W;

  hipMemsetAsync(d_ws, 0, 256, stream);
  hipMemsetAsync(d_out, 0, (size_t)out_size * 4, stream);

  router_cvt_kernel<<<256 + 3*2048, 256, 0, stream>>>(
      x, rw, wg, wu, wd, counts, psum, etok, ewt, wgp, wup, wdp);
  aux_kernel<<<1, 64, 0, stream>>>(counts, psum, out + (size_t)TOK*DIM);

  expert_mfma4_kernel<<<256, 512, 0, stream>>>(
      x, wgp, wup, wdp, counts, etok, ewt, out);
}

// Round 6
// 412.219 us; speedup vs baseline: 8.9641x; 1.0710x over previous
//
#include <hip/hip_runtime.h>
#include <math.h>

#define TOK 8192   // B*S tokens
#define DIM 256    // hidden
#define NE  32     // experts
#define NK  4      // top-k
#define NF  1024   // ffn dim

typedef __bf16 bf16x8 __attribute__((ext_vector_type(8)));
typedef float  f32x4  __attribute__((ext_vector_type(4)));
typedef unsigned short u16x8 __attribute__((ext_vector_type(8)));

__device__ __forceinline__ unsigned short f2b(float f) {
  unsigned u = __builtin_bit_cast(unsigned, f);
  unsigned r = (u + 0x7FFFu + ((u >> 16) & 1u)) >> 16;   // RNE
  return (unsigned short)r;
}

// ---------------- Router (fp32, exact top-k match) ----------------
__global__ __launch_bounds__(256) void router_kernel(
    const float* __restrict__ x, const float* __restrict__ rw,
    int* __restrict__ counts, float* __restrict__ psum,
    int* __restrict__ etok, float* __restrict__ ewt)
{
  __shared__ float xs[32][DIM + 4];
  __shared__ float ws[NE][DIM + 4];
  __shared__ float lg[32][NE];
  __shared__ int hist[NE];
  __shared__ int base[NE];

  const int tid = threadIdx.x;
  const int t0 = blockIdx.x * 32;

  {
    const float4* xg = (const float4*)(x + (size_t)t0 * DIM);
    for (int i = tid; i < 32 * (DIM/4); i += 256) {
      int t = i / (DIM/4), c = i % (DIM/4);
      *(float4*)&xs[t][c*4] = xg[t*(DIM/4)+c];
    }
    const float4* wgp = (const float4*)rw;
    for (int i = tid; i < NE * (DIM/4); i += 256) {
      int e = i / (DIM/4), c = i % (DIM/4);
      *(float4*)&ws[e][c*4] = wgp[e*(DIM/4)+c];
    }
  }
  if (tid < NE) hist[tid] = 0;
  __syncthreads();

  for (int i = 0; i < 4; i++) {
    int idx = i*256 + tid;
    int t = idx >> 5, e = idx & 31;
    float acc = 0.f;
    for (int c = 0; c < DIM/4; c++) {
      float4 a = *(const float4*)&xs[t][c*4];
      float4 b = *(const float4*)&ws[e][c*4];
      acc += a.x*b.x + a.y*b.y + a.z*b.z + a.w*b.w;
    }
    lg[t][e] = acc;
  }
  __syncthreads();

  int ids[NK]; int slots[NK]; float wts[NK];
  if (tid < 32) {
    const int t = tid;
    float l[NE];
    #pragma unroll
    for (int e = 0; e < NE; e++) l[e] = lg[t][e];
    unsigned mask = 0;
    float vals[NK];
    #pragma unroll
    for (int k = 0; k < NK; k++) {
      float best = -INFINITY; int bi = 0;
      for (int e = 0; e < NE; e++)
        if (!((mask >> e) & 1u) && l[e] > best) { best = l[e]; bi = e; }
      mask |= 1u << bi; vals[k] = best; ids[k] = bi;
    }
    float s4 = 0.f;
    #pragma unroll
    for (int k = 0; k < NK; k++) { wts[k] = __expf(vals[k] - vals[0]); s4 += wts[k]; }
    #pragma unroll
    for (int k = 0; k < NK; k++) wts[k] /= s4;
    float s = 0.f;
    for (int e = 0; e < NE; e++) { l[e] = __expf(l[e] - vals[0]); s += l[e]; }
    float inv = 1.f / s;
    for (int e = 0; e < NE; e++) lg[t][e] = l[e] * inv;
    #pragma unroll
    for (int k = 0; k < NK; k++) slots[k] = atomicAdd(&hist[ids[k]], 1);
  }
  __syncthreads();
  if (tid < NE) {
    float s = 0.f;
    for (int t = 0; t < 32; t++) s += lg[t][tid];
    atomicAdd(&psum[tid], s);
    int h = hist[tid];
    base[tid] = h ? atomicAdd(&counts[tid], h) : 0;
  }
  __syncthreads();
  if (tid < 32) {
    #pragma unroll
    for (int k = 0; k < NK; k++) {
      int p = base[ids[k]] + slots[k];
      etok[(size_t)ids[k]*TOK + p] = t0 + tid;
      ewt [(size_t)ids[k]*TOK + p] = wts[k];
    }
  }
}

// ---------------- Aux loss ----------------
__global__ void aux_kernel(const int* __restrict__ counts,
                           const float* __restrict__ psum,
                           float* __restrict__ aux_out)
{
  int tid = threadIdx.x;
  float v = 0.f;
  if (tid < NE) v = (counts[tid] / (float)TOK) * (psum[tid] / (float)TOK);
  #pragma unroll
  for (int off = 32; off; off >>= 1) v += __shfl_down(v, off);
  if (tid == 0) aux_out[0] = (float)NE * v;
}

// ========== Expert FFN: on-the-fly fp32->bf16 staging, m93-style pipeline ==========
// 256 blocks x 512 thr (8 waves: mw=wv&3 token-quarter, nw=wv>>2 f/d half).
// M=128 token tiles, 8 slots/expert, XCD-pinned (expert e -> XCD e&7).
// 64-f chunks, 3 stages each (G,U,D). Per phase: issue next stage's 8 float4
// global loads -> compute this stage from LDS (ds_read_b128 + MFMA) ->
// convert+ds_write next stage -> barrier. Ping-pong 2x32KB LDS slots.
__global__ __launch_bounds__(512, 2) void expert_mfma5_kernel(
    const float* __restrict__ x,
    const float* __restrict__ wg_, const float* __restrict__ wu_,
    const float* __restrict__ wd_,
    const int* __restrict__ counts,
    const int* __restrict__ etok, const float* __restrict__ ewt,
    float* __restrict__ out)
{
  const int b  = blockIdx.x;
  const int j  = b >> 3;
  const int e  = (b & 7) + 8 * (j & 3);   // expert -> XCD b&7
  const int s0 = j >> 2;                  // slot 0..7
  const int cnt = counts[e];

  __shared__ unsigned short stg[2][16384];  // 2 x 32 KB bf16 stage slots
  __shared__ unsigned short hs[128][72];    // 18 KB H tile (64 used + 8 pad)
  __shared__ int   lel[128];
  __shared__ float lwt[128];

  const int tid  = threadIdx.x;
  const int lane = tid & 63;
  const int wv   = tid >> 6;
  const int mw   = wv & 3;      // token quarter (32 tokens)
  const int nw   = wv >> 2;     // f-half (32 f) / d-half (128 d)
  const int q    = lane >> 4;
  const int ln   = lane & 15;

  // per-thread staging LDS offsets (constant across chunks)
  // G/U: granule G=i*512+tid -> f=G>>5, gk=G&31, off = f*256 + ((gk^(f&7))<<3)
  // D  : d=G>>3, fg=G&7,            off = d*64  + ((fg^(d&7))<<3)
  int guOff[4], dOff[4], dRow[4], dFg[4];
  #pragma unroll
  for (int i = 0; i < 4; i++) {
    int G = i*512 + tid;
    int f = G >> 5, gk = G & 31;
    guOff[i] = f*256 + ((gk ^ (f & 7)) << 3);
    int d = G >> 3, fg = G & 7;
    dOff[i] = d*64 + ((fg ^ (d & 7)) << 3);
    dRow[i] = d; dFg[i] = fg;
  }

  const float* wgE = wg_ + (size_t)e * NF * DIM;
  const float* wuE = wu_ + (size_t)e * NF * DIM;
  const float* wdE = wd_ + (size_t)e * DIM * NF;

  const int*   el = etok + (size_t)e * TOK;
  const float* ew = ewt  + (size_t)e * TOK;

  for (int t0 = s0 * 128; t0 < cnt; t0 += 1024) {
    if (tid < 128) {
      int gt = t0 + tid;
      lel[tid] = (gt < cnt) ? el[gt] : -1;
      lwt[tid] = (gt < cnt) ? ew[gt] : 0.f;
    }
    __syncthreads();

    // A-fragments: 32 tokens x K=256 in registers (fp32->bf16)
    bf16x8 xf[2][8];
    #pragma unroll
    for (int m = 0; m < 2; m++) {
      int row = mw*32 + m*16 + ln;
      int tok = lel[row]; if (tok < 0) tok = 0;
      const float* xr = x + (size_t)tok * DIM;
      #pragma unroll
      for (int k = 0; k < 8; k++) {
        float4 a = *(const float4*)(xr + k*32 + q*8);
        float4 c = *(const float4*)(xr + k*32 + q*8 + 4);
        union { bf16x8 v; unsigned short s[8]; } t;
        t.s[0]=f2b(a.x); t.s[1]=f2b(a.y); t.s[2]=f2b(a.z); t.s[3]=f2b(a.w);
        t.s[4]=f2b(c.x); t.s[5]=f2b(c.y); t.s[6]=f2b(c.z); t.s[7]=f2b(c.w);
        xf[m][k] = t.v;
      }
    }

    f32x4 oacc[8][2];
    #pragma unroll
    for (int nt = 0; nt < 8; nt++) { oacc[nt][0] = (f32x4){0,0,0,0}; oacc[nt][1] = (f32x4){0,0,0,0}; }

    unsigned short* pA = stg[0];
    unsigned short* pB = stg[1];
    float4 r[8];

    // prologue: load + write G(0) into pA
    {
      const float4* s4 = (const float4*)wgE;
      #pragma unroll
      for (int i = 0; i < 4; i++) { int G = i*512 + tid; r[2*i] = s4[2*G]; r[2*i+1] = s4[2*G+1]; }
      #pragma unroll
      for (int i = 0; i < 4; i++) {
        u16x8 v;
        v[0]=f2b(r[2*i].x);   v[1]=f2b(r[2*i].y);   v[2]=f2b(r[2*i].z);   v[3]=f2b(r[2*i].w);
        v[4]=f2b(r[2*i+1].x); v[5]=f2b(r[2*i+1].y); v[6]=f2b(r[2*i+1].z); v[7]=f2b(r[2*i+1].w);
        *(u16x8*)&pA[guOff[i]] = v;
      }
    }
    __syncthreads();

    f32x4 ga[2][2];

    for (int ch = 0; ch < 16; ch++) {
      // ============ G phase: compute G(ch) from pA; load+write U(ch) -> pB ============
      {
        const float4* s4 = (const float4*)(wuE + (size_t)ch*16384);
        #pragma unroll
        for (int i = 0; i < 4; i++) { int G = i*512 + tid; r[2*i] = s4[2*G]; r[2*i+1] = s4[2*G+1]; }
      }
      #pragma unroll
      for (int nt = 0; nt < 2; nt++) {
        int fl = nw*32 + nt*16 + ln;
        int rowb = fl*256, xo = fl & 7;
        ga[nt][0] = (f32x4){0,0,0,0}; ga[nt][1] = (f32x4){0,0,0,0};
        #pragma unroll
        for (int kk = 0; kk < 8; kk++) {
          bf16x8 bg = *(const bf16x8*)&pA[rowb + (((kk*4 + q) ^ xo) << 3)];
          ga[nt][0] = __builtin_amdgcn_mfma_f32_16x16x32_bf16(xf[0][kk], bg, ga[nt][0], 0,0,0);
          ga[nt][1] = __builtin_amdgcn_mfma_f32_16x16x32_bf16(xf[1][kk], bg, ga[nt][1], 0,0,0);
        }
      }
      #pragma unroll
      for (int i = 0; i < 4; i++) {
        u16x8 v;
        v[0]=f2b(r[2*i].x);   v[1]=f2b(r[2*i].y);   v[2]=f2b(r[2*i].z);   v[3]=f2b(r[2*i].w);
        v[4]=f2b(r[2*i+1].x); v[5]=f2b(r[2*i+1].y); v[6]=f2b(r[2*i+1].z); v[7]=f2b(r[2*i+1].w);
        *(u16x8*)&pB[guOff[i]] = v;
      }
      __syncthreads();
      { unsigned short* t = pA; pA = pB; pB = t; }

      // ============ U phase: compute U(ch) from pA, silu->hs; load+write D(ch) -> pB ============
      {
        #pragma unroll
        for (int i = 0; i < 4; i++) {
          const float4* p = (const float4*)(wdE + (size_t)dRow[i]*NF + ch*64 + dFg[i]*8);
          r[2*i] = p[0]; r[2*i+1] = p[1];
        }
      }
      #pragma unroll
      for (int nt = 0; nt < 2; nt++) {
        int fl = nw*32 + nt*16 + ln;
        int rowb = fl*256, xo = fl & 7;
        f32x4 ua0 = (f32x4){0,0,0,0}, ua1 = (f32x4){0,0,0,0};
        #pragma unroll
        for (int kk = 0; kk < 8; kk++) {
          bf16x8 bu = *(const bf16x8*)&pA[rowb + (((kk*4 + q) ^ xo) << 3)];
          ua0 = __builtin_amdgcn_mfma_f32_16x16x32_bf16(xf[0][kk], bu, ua0, 0,0,0);
          ua1 = __builtin_amdgcn_mfma_f32_16x16x32_bf16(xf[1][kk], bu, ua1, 0,0,0);
        }
        #pragma unroll
        for (int rr = 0; rr < 4; rr++) {
          float g0 = ga[nt][0][rr], g1 = ga[nt][1][rr];
          hs[mw*32      + q*4 + rr][fl] = f2b((g0 / (1.f + __expf(-g0))) * ua0[rr]);
          hs[mw*32 + 16 + q*4 + rr][fl] = f2b((g1 / (1.f + __expf(-g1))) * ua1[rr]);
        }
      }
      #pragma unroll
      for (int i = 0; i < 4; i++) {
        u16x8 v;
        v[0]=f2b(r[2*i].x);   v[1]=f2b(r[2*i].y);   v[2]=f2b(r[2*i].z);   v[3]=f2b(r[2*i].w);
        v[4]=f2b(r[2*i+1].x); v[5]=f2b(r[2*i+1].y); v[6]=f2b(r[2*i+1].z); v[7]=f2b(r[2*i+1].w);
        *(u16x8*)&pB[dOff[i]] = v;
      }
      __syncthreads();
      { unsigned short* t = pA; pA = pB; pB = t; }

      // ============ D phase: compute D(ch) from pA; load+write G(ch+1) -> pB ============
      if (ch < 15) {
        const float4* s4 = (const float4*)(wgE + (size_t)(ch+1)*16384);
        #pragma unroll
        for (int i = 0; i < 4; i++) { int G = i*512 + tid; r[2*i] = s4[2*G]; r[2*i+1] = s4[2*G+1]; }
      }
      #pragma unroll
      for (int kk = 0; kk < 2; kk++) {
        bf16x8 a0 = *(const bf16x8*)&hs[mw*32      + ln][kk*32 + q*8];
        bf16x8 a1 = *(const bf16x8*)&hs[mw*32 + 16 + ln][kk*32 + q*8];
        #pragma unroll
        for (int nt = 0; nt < 8; nt++) {
          int d = nw*128 + nt*16 + ln;
          bf16x8 bd = *(const bf16x8*)&pA[d*64 + (((kk*4 + q) ^ (d & 7)) << 3)];
          oacc[nt][0] = __builtin_amdgcn_mfma_f32_16x16x32_bf16(a0, bd, oacc[nt][0], 0,0,0);
          oacc[nt][1] = __builtin_amdgcn_mfma_f32_16x16x32_bf16(a1, bd, oacc[nt][1], 0,0,0);
        }
      }
      if (ch < 15) {
        #pragma unroll
        for (int i = 0; i < 4; i++) {
          u16x8 v;
          v[0]=f2b(r[2*i].x);   v[1]=f2b(r[2*i].y);   v[2]=f2b(r[2*i].z);   v[3]=f2b(r[2*i].w);
          v[4]=f2b(r[2*i+1].x); v[5]=f2b(r[2*i+1].y); v[6]=f2b(r[2*i+1].z); v[7]=f2b(r[2*i+1].w);
          *(u16x8*)&pB[guOff[i]] = v;
        }
      }
      __syncthreads();
      { unsigned short* t = pA; pA = pB; pB = t; }
    }

    // epilogue: weighted atomic scatter
    #pragma unroll
    for (int nt = 0; nt < 8; nt++) {
      int d = nw*128 + nt*16 + ln;
      #pragma unroll
      for (int m = 0; m < 2; m++)
        #pragma unroll
        for (int rr = 0; rr < 4; rr++) {
          int tl = mw*32 + m*16 + q*4 + rr;
          int tok = lel[tl];
          if (tok >= 0)
            atomicAdd(&out[(size_t)tok*DIM + d], lwt[tl] * oacc[nt][m][rr]);
        }
    }
    __syncthreads();   // protect lel/lwt/stg before next tile
  }
}

extern "C" void kernel_launch(void* const* d_in, const int* in_sizes, int n_in,
                              void* d_out, int out_size, void* d_ws, size_t ws_size,
                              hipStream_t stream)
{
  const float* x  = (const float*)d_in[0];
  const float* rw = (const float*)d_in[1];
  const float* wg = (const float*)d_in[2];
  const float* wu = (const float*)d_in[3];
  const float* wd = (const float*)d_in[4];
  float* out = (float*)d_out;

  // ws layout (~2.1 MB): counts[32] | psum[32] | etok[E*T] | ewt[E*T]
  int*   counts = (int*)d_ws;
  float* psum   = (float*)((char*)d_ws + 128);
  int*   etok   = (int*)((char*)d_ws + 256);
  float* ewt    = (float*)((char*)d_ws + 256 + (size_t)NE*TOK*4);

  hipMemsetAsync(d_ws, 0, 256, stream);
  hipMemsetAsync(d_out, 0, (size_t)out_size * 4, stream);

  router_kernel<<<TOK/32, 256, 0, stream>>>(x, rw, counts, psum, etok, ewt);
  aux_kernel<<<1, 64, 0, stream>>>(counts, psum, out + (size_t)TOK*DIM);

  expert_mfma5_kernel<<<256, 512, 0, stream>>>(
      x, wg, wu, wd, counts, etok, ewt, out);
}